// Round 1
// baseline (7347.599 us; speedup 1.0000x reference)
//
#include <hip/hip_runtime.h>

constexpr int B_ = 8, C_ = 256, P_ = 64, H_ = 64, W_ = 64, HW_ = 4096;

// ---------------------------------------------------------------------------
// K1: 1x1 convs (top & center). GEMM [P=64, C=256] x [C, HW] per batch.
// blockIdx.y selects top(0)/center(1). Thread owns one column n, 64 p-accs.
// Weights are wave-uniform -> expect s_load_dwordx4.
// ---------------------------------------------------------------------------
__global__ __launch_bounds__(256) void k_conv1x1(
    const float* __restrict__ x,
    const float* __restrict__ w_top, const float* __restrict__ b_top,
    const float* __restrict__ w_cen, const float* __restrict__ b_cen,
    float* __restrict__ xt, float* __restrict__ xc)
{
    const int b = blockIdx.z;
    const int n = blockIdx.x * 256 + threadIdx.x;
    const float* w    = blockIdx.y ? w_cen : w_top;
    const float* bias = blockIdx.y ? b_cen : b_top;
    float* out        = blockIdx.y ? xc : xt;

    const float* xp = x + (size_t)b * C_ * HW_ + n;
    float acc[P_];
#pragma unroll
    for (int p = 0; p < P_; ++p) acc[p] = 0.f;

    for (int c = 0; c < C_; c += 4) {
        const float xv0 = xp[(size_t)(c + 0) * HW_];
        const float xv1 = xp[(size_t)(c + 1) * HW_];
        const float xv2 = xp[(size_t)(c + 2) * HW_];
        const float xv3 = xp[(size_t)(c + 3) * HW_];
#pragma unroll
        for (int p = 0; p < P_; ++p) {
            const float4 wv = *reinterpret_cast<const float4*>(&w[p * C_ + c]);
            float a = acc[p];
            a = fmaf(wv.x, xv0, a);
            a = fmaf(wv.y, xv1, a);
            a = fmaf(wv.z, xv2, a);
            a = fmaf(wv.w, xv3, a);
            acc[p] = a;
        }
    }
    float* op = out + (size_t)b * P_ * HW_ + n;
#pragma unroll
    for (int p = 0; p < P_; ++p) op[(size_t)p * HW_] = acc[p] + bias[p];
}

// ---------------------------------------------------------------------------
// K2/K5: direct 3x3 conv, pad 1, 256->256 channels.
// block 256 = 64 w-lanes x 4 h-rows; thread computes 64 co (one co-group).
// TRANSP=true writes [B,HW,C] (for x_bottom), else [B,C,HW].
// Border handling: clamped offsets * {0,1} mask (branchless, hoisted).
// ---------------------------------------------------------------------------
template <bool TRANSP>
__global__ __launch_bounds__(256) void k_conv3x3(
    const float* __restrict__ xin, const float* __restrict__ wgt,
    const float* __restrict__ bias, float* __restrict__ out)
{
    const int b = blockIdx.z, cog = blockIdx.y;
    const int w = threadIdx.x & 63;
    const int h = blockIdx.x * 4 + (threadIdx.x >> 6);

    int off[9];
    float msk[9];
#pragma unroll
    for (int kh = 0; kh < 3; ++kh) {
#pragma unroll
        for (int kw = 0; kw < 3; ++kw) {
            int hh = h + kh - 1, ww = w + kw - 1;
            const bool v = (hh >= 0) & (hh < H_) & (ww >= 0) & (ww < W_);
            hh = min(max(hh, 0), H_ - 1);
            ww = min(max(ww, 0), W_ - 1);
            off[kh * 3 + kw] = hh * W_ + ww;
            msk[kh * 3 + kw] = v ? 1.f : 0.f;
        }
    }

    float acc[64];
#pragma unroll
    for (int i = 0; i < 64; ++i) acc[i] = 0.f;

    const float* xbase = xin + (size_t)b * C_ * HW_;
    const float* wbase = wgt + (size_t)(cog * 64) * C_ * 9;

    for (int ci = 0; ci < C_; ++ci) {
        const float* xr = xbase + (size_t)ci * HW_;
        float xv[9];
#pragma unroll
        for (int k = 0; k < 9; ++k) xv[k] = xr[off[k]] * msk[k];
        const float* wp = wbase + ci * 9;
#pragma unroll
        for (int co = 0; co < 64; ++co) {
            const float* wq = wp + (size_t)co * (C_ * 9);
            float a = acc[co];
#pragma unroll
            for (int k = 0; k < 9; ++k) a = fmaf(wq[k], xv[k], a);
            acc[co] = a;
        }
    }

    const int pos = h * W_ + w;
    if constexpr (TRANSP) {
        float* op = out + ((size_t)b * HW_ + pos) * C_ + cog * 64;
#pragma unroll
        for (int q = 0; q < 16; ++q) {
            float4 v = { acc[q * 4 + 0] + bias[cog * 64 + q * 4 + 0],
                         acc[q * 4 + 1] + bias[cog * 64 + q * 4 + 1],
                         acc[q * 4 + 2] + bias[cog * 64 + q * 4 + 2],
                         acc[q * 4 + 3] + bias[cog * 64 + q * 4 + 3] };
            *reinterpret_cast<float4*>(&op[q * 4]) = v;
        }
    } else {
        float* op = out + ((size_t)(b * C_ + cog * 64)) * HW_ + pos;
#pragma unroll
        for (int co = 0; co < 64; ++co)
            op[(size_t)co * HW_] = acc[co] + bias[cog * 64 + co];
    }
}

// ---------------------------------------------------------------------------
// K3a: Z[b] = sum_{n,m} exp(S[n,m]),  S = xc^T xt (K=64). 64x64 tile/block.
// No max-subtraction: S ~ N(0,64), max ~49 << 88 (fp32 exp overflow bound).
// ---------------------------------------------------------------------------
__global__ __launch_bounds__(256) void k_score_sum(
    const float* __restrict__ xt, const float* __restrict__ xc,
    float* __restrict__ Z)
{
    __shared__ float xcs[P_][68];
    __shared__ float xts[P_][68];
    __shared__ float wsum[4];
    const int b = blockIdx.z;
    const int n0 = blockIdx.y * 64, m0 = blockIdx.x * 64;
    const int t = threadIdx.x;
    const int col = (t & 15) * 4, pr = t >> 4;
#pragma unroll
    for (int i = 0; i < 4; ++i) {
        const int p = pr + i * 16;
        *reinterpret_cast<float4*>(&xcs[p][col]) =
            *reinterpret_cast<const float4*>(&xc[((size_t)(b * P_ + p)) * HW_ + n0 + col]);
        *reinterpret_cast<float4*>(&xts[p][col]) =
            *reinterpret_cast<const float4*>(&xt[((size_t)(b * P_ + p)) * HW_ + m0 + col]);
    }
    __syncthreads();

    const int tn = (t >> 4) * 4, tm = (t & 15) * 4;
    float s[16];
#pragma unroll
    for (int i = 0; i < 16; ++i) s[i] = 0.f;
#pragma unroll 4
    for (int p = 0; p < P_; ++p) {
        const float4 a4 = *reinterpret_cast<const float4*>(&xcs[p][tn]);
        const float4 b4 = *reinterpret_cast<const float4*>(&xts[p][tm]);
        const float av[4] = {a4.x, a4.y, a4.z, a4.w};
        const float bv[4] = {b4.x, b4.y, b4.z, b4.w};
#pragma unroll
        for (int i = 0; i < 4; ++i)
#pragma unroll
            for (int j = 0; j < 4; ++j)
                s[i * 4 + j] = fmaf(av[i], bv[j], s[i * 4 + j]);
    }
    float part = 0.f;
#pragma unroll
    for (int i = 0; i < 16; ++i) part += __expf(s[i]);
#pragma unroll
    for (int o = 32; o > 0; o >>= 1) part += __shfl_down(part, o, 64);
    if ((t & 63) == 0) wsum[t >> 6] = part;
    __syncthreads();
    if (t == 0) atomicAdd(&Z[b], wsum[0] + wsum[1] + wsum[2] + wsum[3]);
}

// ---------------------------------------------------------------------------
// K3b: O[n,c] = (1/Z) sum_m exp(S[n,m]) * Xb[m,c]. Recomputes S per 64-tile,
// exp into LDS (stride 65 -> <=2-way bank aliasing), then 4n x 16c register
// microtile GEMM against Xb rows read from global (L2-resident, 32 MB).
// ---------------------------------------------------------------------------
__global__ __launch_bounds__(256) void k_attn(
    const float* __restrict__ xt, const float* __restrict__ xc,
    const float* __restrict__ xb, const float* __restrict__ Z,
    float* __restrict__ O)
{
    __shared__ float xcs[P_][68];
    __shared__ float xts[P_][68];
    __shared__ float ps[64][65];
    const int b = blockIdx.y;
    const int n0 = blockIdx.x * 64;
    const int t = threadIdx.x;
    const int col = (t & 15) * 4, pr = t >> 4;
#pragma unroll
    for (int i = 0; i < 4; ++i) {
        const int p = pr + i * 16;
        *reinterpret_cast<float4*>(&xcs[p][col]) =
            *reinterpret_cast<const float4*>(&xc[((size_t)(b * P_ + p)) * HW_ + n0 + col]);
    }
    const float invZ = 1.0f / Z[b];

    const int tn = (t >> 4) * 4, tm = (t & 15) * 4;
    const int nq = t >> 4, c0 = (t & 15) * 16;
    float acc[4][16];
#pragma unroll
    for (int i = 0; i < 4; ++i)
#pragma unroll
        for (int j = 0; j < 16; ++j) acc[i][j] = 0.f;

    for (int mt = 0; mt < 64; ++mt) {
        const int m0 = mt * 64;
#pragma unroll
        for (int i = 0; i < 4; ++i) {
            const int p = pr + i * 16;
            *reinterpret_cast<float4*>(&xts[p][col]) =
                *reinterpret_cast<const float4*>(&xt[((size_t)(b * P_ + p)) * HW_ + m0 + col]);
        }
        __syncthreads();  // xts ready; also guards ps vs previous stage2

        float s[16];
#pragma unroll
        for (int i = 0; i < 16; ++i) s[i] = 0.f;
#pragma unroll 4
        for (int p = 0; p < P_; ++p) {
            const float4 a4 = *reinterpret_cast<const float4*>(&xcs[p][tn]);
            const float4 b4 = *reinterpret_cast<const float4*>(&xts[p][tm]);
            const float av[4] = {a4.x, a4.y, a4.z, a4.w};
            const float bv[4] = {b4.x, b4.y, b4.z, b4.w};
#pragma unroll
            for (int i = 0; i < 4; ++i)
#pragma unroll
                for (int j = 0; j < 4; ++j)
                    s[i * 4 + j] = fmaf(av[i], bv[j], s[i * 4 + j]);
        }
#pragma unroll
        for (int i = 0; i < 4; ++i)
#pragma unroll
            for (int j = 0; j < 4; ++j)
                ps[tn + i][tm + j] = __expf(s[i * 4 + j]);
        __syncthreads();  // ps ready

        const float* xrow = xb + ((size_t)(b * HW_ + m0)) * C_ + c0;
        for (int m = 0; m < 64; ++m) {
            const float pv0 = ps[nq * 4 + 0][m];
            const float pv1 = ps[nq * 4 + 1][m];
            const float pv2 = ps[nq * 4 + 2][m];
            const float pv3 = ps[nq * 4 + 3][m];
            const float4 x0 = *reinterpret_cast<const float4*>(&xrow[0]);
            const float4 x1 = *reinterpret_cast<const float4*>(&xrow[4]);
            const float4 x2 = *reinterpret_cast<const float4*>(&xrow[8]);
            const float4 x3 = *reinterpret_cast<const float4*>(&xrow[12]);
            const float xv[16] = {x0.x, x0.y, x0.z, x0.w, x1.x, x1.y, x1.z, x1.w,
                                  x2.x, x2.y, x2.z, x2.w, x3.x, x3.y, x3.z, x3.w};
#pragma unroll
            for (int j = 0; j < 16; ++j) {
                acc[0][j] = fmaf(pv0, xv[j], acc[0][j]);
                acc[1][j] = fmaf(pv1, xv[j], acc[1][j]);
                acc[2][j] = fmaf(pv2, xv[j], acc[2][j]);
                acc[3][j] = fmaf(pv3, xv[j], acc[3][j]);
            }
            xrow += C_;
        }
    }

#pragma unroll
    for (int i = 0; i < 4; ++i) {
        float* op = O + ((size_t)(b * HW_ + n0 + nq * 4 + i)) * C_ + c0;
#pragma unroll
        for (int q = 0; q < 4; ++q) {
            float4 v = { acc[i][q * 4 + 0] * invZ, acc[i][q * 4 + 1] * invZ,
                         acc[i][q * 4 + 2] * invZ, acc[i][q * 4 + 3] * invZ };
            *reinterpret_cast<float4*>(&op[q * 4]) = v;
        }
    }
}

// ---------------------------------------------------------------------------
// K4: y = x + O (flat). The [B,HW,C]->[B,C,H,W] reshape is a pure memory
// reinterpretation, so flat indices coincide.
// ---------------------------------------------------------------------------
__global__ __launch_bounds__(256) void k_add(
    const float* __restrict__ x, const float* __restrict__ o,
    float* __restrict__ y)
{
    const size_t i = ((size_t)blockIdx.x * 256 + threadIdx.x) * 4;
    const float4 a = *reinterpret_cast<const float4*>(&x[i]);
    const float4 b = *reinterpret_cast<const float4*>(&o[i]);
    float4 r{a.x + b.x, a.y + b.y, a.z + b.z, a.w + b.w};
    *reinterpret_cast<float4*>(&y[i]) = r;
}

extern "C" void kernel_launch(void* const* d_in, const int* in_sizes, int n_in,
                              void* d_out, int out_size, void* d_ws, size_t ws_size,
                              hipStream_t stream)
{
    const float* x   = (const float*)d_in[0];
    const float* wt  = (const float*)d_in[1];
    const float* bt  = (const float*)d_in[2];
    const float* wc  = (const float*)d_in[3];
    const float* bc  = (const float*)d_in[4];
    const float* wb  = (const float*)d_in[5];
    const float* bbo = (const float*)d_in[6];
    const float* wo  = (const float*)d_in[7];
    const float* bo  = (const float*)d_in[8];
    float* out = (float*)d_out;

    float* ws = (float*)d_ws;
    float* xt = ws;                                 // [B,P,HW]   8 MB
    float* xc = xt + (size_t)B_ * P_ * HW_;         // [B,P,HW]   8 MB
    float* xb = xc + (size_t)B_ * P_ * HW_;         // [B,HW,C]  32 MB (reused as y)
    float* O  = xb + (size_t)B_ * HW_ * C_;         // [B,HW,C]  32 MB
    float* Z  = O  + (size_t)B_ * HW_ * C_;         // [B]

    hipMemsetAsync(Z, 0, B_ * sizeof(float), stream);
    k_conv1x1<<<dim3(16, 2, 8), 256, 0, stream>>>(x, wt, bt, wc, bc, xt, xc);
    k_conv3x3<true ><<<dim3(16, 4, 8), 256, 0, stream>>>(x, wb, bbo, xb);
    k_score_sum<<<dim3(64, 64, 8), 256, 0, stream>>>(xt, xc, Z);
    k_attn<<<dim3(64, 8), 256, 0, stream>>>(xt, xc, xb, Z, O);
    k_add<<<dim3(8192), 256, 0, stream>>>(x, O, xb);       // y overwrites xb
    k_conv3x3<false><<<dim3(16, 4, 8), 256, 0, stream>>>(xb, wo, bo, out);
}

// Round 2
// 2748.012 us; speedup vs baseline: 2.6738x; 2.6738x over previous
//
#include <hip/hip_runtime.h>
#include <hip/hip_bf16.h>

constexpr int B_ = 8, C_ = 256, P_ = 64, H_ = 64, W_ = 64, HW_ = 4096;

typedef __attribute__((ext_vector_type(8))) short short8;   // 8 bf16 (4 VGPRs)
typedef __attribute__((ext_vector_type(4))) float f32x4;

// ---------------------------------------------------------------------------
// K0: weight prep. w fp32 [co][ci][3][3] (OIHW) -> wb bf16 [tap][co][ci].
// Tiny (590k elems); runs into dead workspace phases.
// ---------------------------------------------------------------------------
__global__ __launch_bounds__(256) void k_prep_w(
    const float* __restrict__ w, __hip_bfloat16* __restrict__ wb)
{
    const int i = blockIdx.x * 256 + threadIdx.x;        // over 9*256*256
    const int tap = i >> 16;
    const int co  = (i >> 8) & 255;
    const int ci  = i & 255;
    wb[i] = __float2bfloat16(w[(co * 256 + ci) * 9 + tap]);
}

// ---------------------------------------------------------------------------
// K1: 1x1 convs (top & center). GEMM [P=64, C=256] x [C, HW] per batch.
// ---------------------------------------------------------------------------
__global__ __launch_bounds__(256) void k_conv1x1(
    const float* __restrict__ x,
    const float* __restrict__ w_top, const float* __restrict__ b_top,
    const float* __restrict__ w_cen, const float* __restrict__ b_cen,
    float* __restrict__ xt, float* __restrict__ xc)
{
    const int b = blockIdx.z;
    const int n = blockIdx.x * 256 + threadIdx.x;
    const float* w    = blockIdx.y ? w_cen : w_top;
    const float* bias = blockIdx.y ? b_cen : b_top;
    float* out        = blockIdx.y ? xc : xt;

    const float* xp = x + (size_t)b * C_ * HW_ + n;
    float acc[P_];
#pragma unroll
    for (int p = 0; p < P_; ++p) acc[p] = 0.f;

    for (int c = 0; c < C_; c += 4) {
        const float xv0 = xp[(size_t)(c + 0) * HW_];
        const float xv1 = xp[(size_t)(c + 1) * HW_];
        const float xv2 = xp[(size_t)(c + 2) * HW_];
        const float xv3 = xp[(size_t)(c + 3) * HW_];
#pragma unroll
        for (int p = 0; p < P_; ++p) {
            const float4 wv = *reinterpret_cast<const float4*>(&w[p * C_ + c]);
            float a = acc[p];
            a = fmaf(wv.x, xv0, a);
            a = fmaf(wv.y, xv1, a);
            a = fmaf(wv.z, xv2, a);
            a = fmaf(wv.w, xv3, a);
            acc[p] = a;
        }
    }
    float* op = out + (size_t)b * P_ * HW_ + n;
#pragma unroll
    for (int p = 0; p < P_; ++p) op[(size_t)p * HW_] = acc[p] + bias[p];
}

// ---------------------------------------------------------------------------
// K2/K5: 3x3 conv as implicit GEMM on bf16 MFMA 16x16x32 (fp32 accumulate).
// Block = (batch b, row h): C-tile [256 co][64 w]. 4 waves x (4 co-tiles x
// 4 n-tiles) of 16x16. K-loop: 8 ci-blocks of 32 x 9 taps, 1 mfma each.
// X staged to LDS ci-contiguous with zeroed w-halo (border masking free);
// row stride 40 bf16 = 80 B -> 16B-aligned ds_read_b128, ~2-way banks (free).
// A-frags (weights) read from global wb [tap][co][ci] (L2-resident, 1.2 MB).
// ---------------------------------------------------------------------------
template <bool TRANSP>
__global__ __launch_bounds__(256) void k_conv3x3_mfma(
    const float* __restrict__ xin, const __hip_bfloat16* __restrict__ wb,
    const float* __restrict__ bias, float* __restrict__ out)
{
    __shared__ __align__(16) __hip_bfloat16 Xs[3][66][40];
    const int b = blockIdx.y, h = blockIdx.x;
    const int t = threadIdx.x;
    const int wave = t >> 6, lane = t & 63;
    const int lm = lane & 15, lq = lane >> 4;

    f32x4 acc[4][4];   // [n_tile][co_tile]
#pragma unroll
    for (int i = 0; i < 4; ++i)
#pragma unroll
        for (int j = 0; j < 4; ++j) acc[i][j] = f32x4{0.f, 0.f, 0.f, 0.f};

    // zero w-halo columns once (never overwritten by staging)
    if (t < 192) {
        const int r = t >> 6, cc = t & 31, side = (t >> 5) & 1;
        Xs[r][side ? 65 : 0][cc] = __float2bfloat16(0.f);
    }

    const int ci_ld = t & 31;    // staging: ci lane
    const int grp   = t >> 5;    // staging: 0..7
    const float* xbase = xin + (size_t)b * C_ * HW_;

    for (int cb = 0; cb < 8; ++cb) {
        const int ci0 = cb * 32;
        __syncthreads();   // Xs free (also makes halo zeros visible on cb=0)
#pragma unroll
        for (int it = 0; it < 6; ++it) {
            const int qr = it * 8 + grp;        // 0..47 quad-rows
            const int r = qr >> 4, wq = qr & 15;
            const int hh = h + r - 1;
            float4 v = {0.f, 0.f, 0.f, 0.f};
            if (hh >= 0 && hh < H_)
                v = *reinterpret_cast<const float4*>(
                    &xbase[(size_t)(ci0 + ci_ld) * HW_ + hh * W_ + wq * 4]);
            Xs[r][1 + wq * 4 + 0][ci_ld] = __float2bfloat16(v.x);
            Xs[r][1 + wq * 4 + 1][ci_ld] = __float2bfloat16(v.y);
            Xs[r][1 + wq * 4 + 2][ci_ld] = __float2bfloat16(v.z);
            Xs[r][1 + wq * 4 + 3][ci_ld] = __float2bfloat16(v.w);
        }
        __syncthreads();   // Xs ready

        for (int tap = 0; tap < 9; ++tap) {
            const int dh = tap / 3;      // LDS row 0..2  (input row h+dh-1)
            const int dw = tap % 3;      // halo index shift: w' = n+dw-1 -> idx n+dw
            short8 bf[4];
#pragma unroll
            for (int nt = 0; nt < 4; ++nt)
                bf[nt] = *reinterpret_cast<const short8*>(
                    &Xs[dh][nt * 16 + lm + dw][lq * 8]);
            short8 af[4];
            const __hip_bfloat16* wt = wb + ((size_t)tap * C_) * C_ + ci0 + lq * 8;
#pragma unroll
            for (int ct = 0; ct < 4; ++ct) {
                const int co = wave * 64 + ct * 16 + lm;
                af[ct] = *reinterpret_cast<const short8*>(&wt[(size_t)co * C_]);
            }
#pragma unroll
            for (int nt = 0; nt < 4; ++nt)
#pragma unroll
                for (int ct = 0; ct < 4; ++ct)
                    acc[nt][ct] = __builtin_amdgcn_mfma_f32_16x16x32_bf16(
                        af[ct], bf[nt], acc[nt][ct], 0, 0, 0);
        }
    }

    // Epilogue. C/D layout 16x16x32: col(n)=lane&15, row(co)=lq*4+reg.
    if constexpr (TRANSP) {  // out [B][HW][C]: 4 regs = 4 consecutive co
#pragma unroll
        for (int nt = 0; nt < 4; ++nt) {
            const int pos = h * W_ + nt * 16 + lm;
#pragma unroll
            for (int ct = 0; ct < 4; ++ct) {
                const int co = wave * 64 + ct * 16 + lq * 4;
                const float4 bv = *reinterpret_cast<const float4*>(&bias[co]);
                float4 r = { acc[nt][ct][0] + bv.x, acc[nt][ct][1] + bv.y,
                             acc[nt][ct][2] + bv.z, acc[nt][ct][3] + bv.w };
                *reinterpret_cast<float4*>(
                    &out[((size_t)b * HW_ + pos) * C_ + co]) = r;
            }
        }
    } else {                 // out [B][C][HW]
#pragma unroll
        for (int nt = 0; nt < 4; ++nt) {
            const int pos = h * W_ + nt * 16 + lm;
#pragma unroll
            for (int ct = 0; ct < 4; ++ct) {
                const int co = wave * 64 + ct * 16 + lq * 4;
#pragma unroll
                for (int r = 0; r < 4; ++r)
                    out[((size_t)b * C_ + co + r) * HW_ + pos] =
                        acc[nt][ct][r] + bias[co + r];
            }
        }
    }
}

// ---------------------------------------------------------------------------
// K3a: Z[b] = sum_{n,m} exp(S[n,m]),  S = xc^T xt (K=64). 64x64 tile/block.
// ---------------------------------------------------------------------------
__global__ __launch_bounds__(256) void k_score_sum(
    const float* __restrict__ xt, const float* __restrict__ xc,
    float* __restrict__ Z)
{
    __shared__ float xcs[P_][68];
    __shared__ float xts[P_][68];
    __shared__ float wsum[4];
    const int b = blockIdx.z;
    const int n0 = blockIdx.y * 64, m0 = blockIdx.x * 64;
    const int t = threadIdx.x;
    const int col = (t & 15) * 4, pr = t >> 4;
#pragma unroll
    for (int i = 0; i < 4; ++i) {
        const int p = pr + i * 16;
        *reinterpret_cast<float4*>(&xcs[p][col]) =
            *reinterpret_cast<const float4*>(&xc[((size_t)(b * P_ + p)) * HW_ + n0 + col]);
        *reinterpret_cast<float4*>(&xts[p][col]) =
            *reinterpret_cast<const float4*>(&xt[((size_t)(b * P_ + p)) * HW_ + m0 + col]);
    }
    __syncthreads();

    const int tn = (t >> 4) * 4, tm = (t & 15) * 4;
    float s[16];
#pragma unroll
    for (int i = 0; i < 16; ++i) s[i] = 0.f;
#pragma unroll 4
    for (int p = 0; p < P_; ++p) {
        const float4 a4 = *reinterpret_cast<const float4*>(&xcs[p][tn]);
        const float4 b4 = *reinterpret_cast<const float4*>(&xts[p][tm]);
        const float av[4] = {a4.x, a4.y, a4.z, a4.w};
        const float bv[4] = {b4.x, b4.y, b4.z, b4.w};
#pragma unroll
        for (int i = 0; i < 4; ++i)
#pragma unroll
            for (int j = 0; j < 4; ++j)
                s[i * 4 + j] = fmaf(av[i], bv[j], s[i * 4 + j]);
    }
    float part = 0.f;
#pragma unroll
    for (int i = 0; i < 16; ++i) part += __expf(s[i]);
#pragma unroll
    for (int o = 32; o > 0; o >>= 1) part += __shfl_down(part, o, 64);
    if ((t & 63) == 0) wsum[t >> 6] = part;
    __syncthreads();
    if (t == 0) atomicAdd(&Z[b], wsum[0] + wsum[1] + wsum[2] + wsum[3]);
}

// ---------------------------------------------------------------------------
// K3b: O[n,c] = (1/Z) sum_m exp(S[n,m]) * Xb[m,c]. Flash-style recompute.
// ---------------------------------------------------------------------------
__global__ __launch_bounds__(256) void k_attn(
    const float* __restrict__ xt, const float* __restrict__ xc,
    const float* __restrict__ xb, const float* __restrict__ Z,
    float* __restrict__ O)
{
    __shared__ float xcs[P_][68];
    __shared__ float xts[P_][68];
    __shared__ float ps[64][65];
    const int b = blockIdx.y;
    const int n0 = blockIdx.x * 64;
    const int t = threadIdx.x;
    const int col = (t & 15) * 4, pr = t >> 4;
#pragma unroll
    for (int i = 0; i < 4; ++i) {
        const int p = pr + i * 16;
        *reinterpret_cast<float4*>(&xcs[p][col]) =
            *reinterpret_cast<const float4*>(&xc[((size_t)(b * P_ + p)) * HW_ + n0 + col]);
    }
    const float invZ = 1.0f / Z[b];

    const int tn = (t >> 4) * 4, tm = (t & 15) * 4;
    const int nq = t >> 4, c0 = (t & 15) * 16;
    float acc[4][16];
#pragma unroll
    for (int i = 0; i < 4; ++i)
#pragma unroll
        for (int j = 0; j < 16; ++j) acc[i][j] = 0.f;

    for (int mt = 0; mt < 64; ++mt) {
        const int m0 = mt * 64;
#pragma unroll
        for (int i = 0; i < 4; ++i) {
            const int p = pr + i * 16;
            *reinterpret_cast<float4*>(&xts[p][col]) =
                *reinterpret_cast<const float4*>(&xt[((size_t)(b * P_ + p)) * HW_ + m0 + col]);
        }
        __syncthreads();

        float s[16];
#pragma unroll
        for (int i = 0; i < 16; ++i) s[i] = 0.f;
#pragma unroll 4
        for (int p = 0; p < P_; ++p) {
            const float4 a4 = *reinterpret_cast<const float4*>(&xcs[p][tn]);
            const float4 b4 = *reinterpret_cast<const float4*>(&xts[p][tm]);
            const float av[4] = {a4.x, a4.y, a4.z, a4.w};
            const float bv[4] = {b4.x, b4.y, b4.z, b4.w};
#pragma unroll
            for (int i = 0; i < 4; ++i)
#pragma unroll
                for (int j = 0; j < 4; ++j)
                    s[i * 4 + j] = fmaf(av[i], bv[j], s[i * 4 + j]);
        }
#pragma unroll
        for (int i = 0; i < 4; ++i)
#pragma unroll
            for (int j = 0; j < 4; ++j)
                ps[tn + i][tm + j] = __expf(s[i * 4 + j]);
        __syncthreads();

        const float* xrow = xb + ((size_t)(b * HW_ + m0)) * C_ + c0;
        for (int m = 0; m < 64; ++m) {
            const float pv0 = ps[nq * 4 + 0][m];
            const float pv1 = ps[nq * 4 + 1][m];
            const float pv2 = ps[nq * 4 + 2][m];
            const float pv3 = ps[nq * 4 + 3][m];
            const float4 x0 = *reinterpret_cast<const float4*>(&xrow[0]);
            const float4 x1 = *reinterpret_cast<const float4*>(&xrow[4]);
            const float4 x2 = *reinterpret_cast<const float4*>(&xrow[8]);
            const float4 x3 = *reinterpret_cast<const float4*>(&xrow[12]);
            const float xv[16] = {x0.x, x0.y, x0.z, x0.w, x1.x, x1.y, x1.z, x1.w,
                                  x2.x, x2.y, x2.z, x2.w, x3.x, x3.y, x3.z, x3.w};
#pragma unroll
            for (int j = 0; j < 16; ++j) {
                acc[0][j] = fmaf(pv0, xv[j], acc[0][j]);
                acc[1][j] = fmaf(pv1, xv[j], acc[1][j]);
                acc[2][j] = fmaf(pv2, xv[j], acc[2][j]);
                acc[3][j] = fmaf(pv3, xv[j], acc[3][j]);
            }
            xrow += C_;
        }
    }

#pragma unroll
    for (int i = 0; i < 4; ++i) {
        float* op = O + ((size_t)(b * HW_ + n0 + nq * 4 + i)) * C_ + c0;
#pragma unroll
        for (int q = 0; q < 4; ++q) {
            float4 v = { acc[i][q * 4 + 0] * invZ, acc[i][q * 4 + 1] * invZ,
                         acc[i][q * 4 + 2] * invZ, acc[i][q * 4 + 3] * invZ };
            *reinterpret_cast<float4*>(&op[q * 4]) = v;
        }
    }
}

// ---------------------------------------------------------------------------
// K4: y = x + O (flat reinterpretation add).
// ---------------------------------------------------------------------------
__global__ __launch_bounds__(256) void k_add(
    const float* __restrict__ x, const float* __restrict__ o,
    float* __restrict__ y)
{
    const size_t i = ((size_t)blockIdx.x * 256 + threadIdx.x) * 4;
    const float4 a = *reinterpret_cast<const float4*>(&x[i]);
    const float4 b = *reinterpret_cast<const float4*>(&o[i]);
    float4 r{a.x + b.x, a.y + b.y, a.z + b.z, a.w + b.w};
    *reinterpret_cast<float4*>(&y[i]) = r;
}

extern "C" void kernel_launch(void* const* d_in, const int* in_sizes, int n_in,
                              void* d_out, int out_size, void* d_ws, size_t ws_size,
                              hipStream_t stream)
{
    const float* x   = (const float*)d_in[0];
    const float* wt  = (const float*)d_in[1];
    const float* bt  = (const float*)d_in[2];
    const float* wc  = (const float*)d_in[3];
    const float* bc  = (const float*)d_in[4];
    const float* wbo = (const float*)d_in[5];
    const float* bbo = (const float*)d_in[6];
    const float* wo  = (const float*)d_in[7];
    const float* bo  = (const float*)d_in[8];
    float* out = (float*)d_out;

    float* ws = (float*)d_ws;
    float* xt = ws;                                 // [B,P,HW]   8 MB
    float* xc = xt + (size_t)B_ * P_ * HW_;         // [B,P,HW]   8 MB
    float* xb = xc + (size_t)B_ * P_ * HW_;         // [B,HW,C]  32 MB (reused as y)
    float* O  = xb + (size_t)B_ * HW_ * C_;         // [B,HW,C]  32 MB
    float* Z  = O  + (size_t)B_ * HW_ * C_;         // [B]

    // weight images live in dead workspace phases:
    // Wb1 (conv-bottom) in O (k_attn writes O only after conv-bottom is done);
    // Wb2 (conv-out) in xt (dead after k_attn).
    __hip_bfloat16* Wb1 = (__hip_bfloat16*)O;
    __hip_bfloat16* Wb2 = (__hip_bfloat16*)xt;

    hipMemsetAsync(Z, 0, B_ * sizeof(float), stream);
    k_prep_w<<<dim3(2304), 256, 0, stream>>>(wbo, Wb1);
    k_conv1x1<<<dim3(16, 2, 8), 256, 0, stream>>>(x, wt, bt, wc, bc, xt, xc);
    k_conv3x3_mfma<true ><<<dim3(64, 8), 256, 0, stream>>>(x, Wb1, bbo, xb);
    k_score_sum<<<dim3(64, 64, 8), 256, 0, stream>>>(xt, xc, Z);
    k_attn<<<dim3(64, 8), 256, 0, stream>>>(xt, xc, xb, Z, O);
    k_prep_w<<<dim3(2304), 256, 0, stream>>>(wo, Wb2);
    k_add<<<dim3(8192), 256, 0, stream>>>(x, O, xb);       // y overwrites xb
    k_conv3x3_mfma<false><<<dim3(64, 8), 256, 0, stream>>>(xb, Wb2, bo, out);
}

// Round 3
// 991.429 us; speedup vs baseline: 7.4111x; 2.7718x over previous
//
#include <hip/hip_runtime.h>
#include <hip/hip_bf16.h>
#include <type_traits>

constexpr int B_ = 8, C_ = 256, P_ = 64, H_ = 64, W_ = 64, HW_ = 4096;

typedef __attribute__((ext_vector_type(8))) short short8;   // 8 bf16
typedef __attribute__((ext_vector_type(4))) short short4v;  // 4 bf16 (8 B)
typedef __attribute__((ext_vector_type(4))) float f32x4;

__device__ __forceinline__ short bfbits(float f) {
    __hip_bfloat16 h = __float2bfloat16(f);
    return *reinterpret_cast<short*>(&h);
}
__device__ __forceinline__ float bf2f(short s) {
    __hip_bfloat16 h = *reinterpret_cast<__hip_bfloat16*>(&s);
    return (float)h;
}

// ---------------------------------------------------------------------------
// K0: weight prep. w fp32 [co][ci][3][3] (OIHW) -> wb bf16 [tap][co][ci].
// ---------------------------------------------------------------------------
__global__ __launch_bounds__(256) void k_prep_w(
    const float* __restrict__ w, __hip_bfloat16* __restrict__ wb)
{
    const int i = blockIdx.x * 256 + threadIdx.x;        // over 9*256*256
    const int tap = i >> 16;
    const int co  = (i >> 8) & 255;
    const int ci  = i & 255;
    wb[i] = __float2bfloat16(w[(co * 256 + ci) * 9 + tap]);
}

// ---------------------------------------------------------------------------
// K1: 1x1 convs. GEMM [P=64, C=256] x [C, HW]. Outputs transposed bf16
// hi/lo splits [B][HW][P] — the exact operand layout k_attn's MFMA wants.
// ---------------------------------------------------------------------------
__global__ __launch_bounds__(256) void k_conv1x1(
    const float* __restrict__ x,
    const float* __restrict__ w_top, const float* __restrict__ b_top,
    const float* __restrict__ w_cen, const float* __restrict__ b_cen,
    __hip_bfloat16* __restrict__ xtTh, __hip_bfloat16* __restrict__ xtTl,
    __hip_bfloat16* __restrict__ xcTh, __hip_bfloat16* __restrict__ xcTl)
{
    const int b = blockIdx.z;
    const int n = blockIdx.x * 256 + threadIdx.x;
    const float* w    = blockIdx.y ? w_cen : w_top;
    const float* bias = blockIdx.y ? b_cen : b_top;
    __hip_bfloat16* oh = blockIdx.y ? xcTh : xtTh;
    __hip_bfloat16* ol = blockIdx.y ? xcTl : xtTl;

    const float* xp = x + (size_t)b * C_ * HW_ + n;
    float acc[P_];
#pragma unroll
    for (int p = 0; p < P_; ++p) acc[p] = 0.f;

    for (int c = 0; c < C_; c += 4) {
        const float xv0 = xp[(size_t)(c + 0) * HW_];
        const float xv1 = xp[(size_t)(c + 1) * HW_];
        const float xv2 = xp[(size_t)(c + 2) * HW_];
        const float xv3 = xp[(size_t)(c + 3) * HW_];
#pragma unroll
        for (int p = 0; p < P_; ++p) {
            const float4 wv = *reinterpret_cast<const float4*>(&w[p * C_ + c]);
            float a = acc[p];
            a = fmaf(wv.x, xv0, a);
            a = fmaf(wv.y, xv1, a);
            a = fmaf(wv.z, xv2, a);
            a = fmaf(wv.w, xv3, a);
            acc[p] = a;
        }
    }
    const size_t rbase = ((size_t)b * HW_ + n) * P_;
#pragma unroll
    for (int j = 0; j < 8; ++j) {
        short8 vh, vl;
#pragma unroll
        for (int k = 0; k < 8; ++k) {
            const float v = acc[j * 8 + k] + bias[j * 8 + k];
            const short hb = bfbits(v);
            vh[k] = hb;
            vl[k] = bfbits(v - bf2f(hb));   // residual for hi/lo split
        }
        *reinterpret_cast<short8*>(&oh[rbase + j * 8]) = vh;
        *reinterpret_cast<short8*>(&ol[rbase + j * 8]) = vl;
    }
}

// ---------------------------------------------------------------------------
// K2/K5: 3x3 conv as implicit GEMM, bf16 MFMA 16x16x32 (fp32 acc).
// Output [B][C][HW], dtype templated (bf16 for conv-bottom, fp32 for conv-out).
// ---------------------------------------------------------------------------
template <typename OT>
__global__ __launch_bounds__(256) void k_conv3x3_mfma(
    const float* __restrict__ xin, const __hip_bfloat16* __restrict__ wb,
    const float* __restrict__ bias, OT* __restrict__ out)
{
    __shared__ __align__(16) __hip_bfloat16 Xs[3][66][40];
    const int b = blockIdx.y, h = blockIdx.x;
    const int t = threadIdx.x;
    const int wave = t >> 6, lane = t & 63;
    const int lm = lane & 15, lq = lane >> 4;

    f32x4 acc[4][4];   // [n_tile][co_tile]
#pragma unroll
    for (int i = 0; i < 4; ++i)
#pragma unroll
        for (int j = 0; j < 4; ++j) acc[i][j] = f32x4{0.f, 0.f, 0.f, 0.f};

    if (t < 192) {   // zero w-halo columns once
        const int r = t >> 6, cc = t & 31, side = (t >> 5) & 1;
        Xs[r][side ? 65 : 0][cc] = __float2bfloat16(0.f);
    }

    const int ci_ld = t & 31;
    const int grp   = t >> 5;
    const float* xbase = xin + (size_t)b * C_ * HW_;

    for (int cb = 0; cb < 8; ++cb) {
        const int ci0 = cb * 32;
        __syncthreads();
#pragma unroll
        for (int it = 0; it < 6; ++it) {
            const int qr = it * 8 + grp;
            const int r = qr >> 4, wq = qr & 15;
            const int hh = h + r - 1;
            float4 v = {0.f, 0.f, 0.f, 0.f};
            if (hh >= 0 && hh < H_)
                v = *reinterpret_cast<const float4*>(
                    &xbase[(size_t)(ci0 + ci_ld) * HW_ + hh * W_ + wq * 4]);
            Xs[r][1 + wq * 4 + 0][ci_ld] = __float2bfloat16(v.x);
            Xs[r][1 + wq * 4 + 1][ci_ld] = __float2bfloat16(v.y);
            Xs[r][1 + wq * 4 + 2][ci_ld] = __float2bfloat16(v.z);
            Xs[r][1 + wq * 4 + 3][ci_ld] = __float2bfloat16(v.w);
        }
        __syncthreads();

        for (int tap = 0; tap < 9; ++tap) {
            const int dh = tap / 3;
            const int dw = tap % 3;
            short8 bf[4];
#pragma unroll
            for (int nt = 0; nt < 4; ++nt)
                bf[nt] = *reinterpret_cast<const short8*>(
                    &Xs[dh][nt * 16 + lm + dw][lq * 8]);
            short8 af[4];
            const __hip_bfloat16* wt = wb + ((size_t)tap * C_) * C_ + ci0 + lq * 8;
#pragma unroll
            for (int ct = 0; ct < 4; ++ct) {
                const int co = wave * 64 + ct * 16 + lm;
                af[ct] = *reinterpret_cast<const short8*>(&wt[(size_t)co * C_]);
            }
#pragma unroll
            for (int nt = 0; nt < 4; ++nt)
#pragma unroll
                for (int ct = 0; ct < 4; ++ct)
                    acc[nt][ct] = __builtin_amdgcn_mfma_f32_16x16x32_bf16(
                        af[ct], bf[nt], acc[nt][ct], 0, 0, 0);
        }
    }

    // Epilogue [B][C][HW]. C/D: col(n)=lane&15, row(co)=lq*4+reg.
#pragma unroll
    for (int nt = 0; nt < 4; ++nt) {
        const int pos = h * W_ + nt * 16 + lm;
#pragma unroll
        for (int ct = 0; ct < 4; ++ct) {
            const int co = wave * 64 + ct * 16 + lq * 4;
#pragma unroll
            for (int r = 0; r < 4; ++r) {
                const float v = acc[nt][ct][r] + bias[co + r];
                if constexpr (std::is_same<OT, __hip_bfloat16>::value)
                    out[((size_t)(b * C_ + co + r)) * HW_ + pos] = __float2bfloat16(v);
                else
                    out[((size_t)(b * C_ + co + r)) * HW_ + pos] = v;
            }
        }
    }
}

// ---------------------------------------------------------------------------
// K3: fused attention, all-MFMA. Block = 64-row n-stripe of one batch.
// Per m-tile (64): S^T = xt^T(m-rows) x xc(n-cols) via 16x16x32 bf16 MFMA
// with hi/lo split (3 products, S error ~1e-4); exp -> P[n][m] bf16 in LDS
// (C/D reg-quad = 4 contiguous m -> ds_write_b64); PV: A=P (lane=n, k=m
// contig), B=xb[c][m] direct from global (natural conv layout). O and Z
// accumulated unnormalized; 1/Z applied in k_add. Z via atomicAdd per block.
// ---------------------------------------------------------------------------
__global__ __launch_bounds__(256) void k_attn_mfma(
    const __hip_bfloat16* __restrict__ xtTh, const __hip_bfloat16* __restrict__ xtTl,
    const __hip_bfloat16* __restrict__ xcTh, const __hip_bfloat16* __restrict__ xcTl,
    const __hip_bfloat16* __restrict__ xb, float* __restrict__ O,
    float* __restrict__ Z)
{
    __shared__ __align__(16) short Ps[64][72];   // P[n][m], stride 72 (144 B)
    __shared__ float zred[4];
    const int b = blockIdx.y, n0 = blockIdx.x * 64;
    const int t = threadIdx.x, wv = t >> 6, lane = t & 63;
    const int lm = lane & 15, lq = lane >> 4;
    const int mq = wv;   // S^T phase: wave's m-quarter
    const int nq = wv;   // PV  phase: wave's n-quarter

    // Hoisted S^T B-frags: xc cols n (block-invariant). [nt][kc][hi/lo]
    short8 cB[4][2][2];
#pragma unroll
    for (int nt = 0; nt < 4; ++nt) {
        const size_t r = ((size_t)b * HW_ + n0 + nt * 16 + lm) * P_ + lq * 8;
#pragma unroll
        for (int kc = 0; kc < 2; ++kc) {
            cB[nt][kc][0] = *reinterpret_cast<const short8*>(&xcTh[r + kc * 32]);
            cB[nt][kc][1] = *reinterpret_cast<const short8*>(&xcTl[r + kc * 32]);
        }
    }

    f32x4 acc[16];   // O[n-quarter][256 c]: 16 c-tiles
#pragma unroll
    for (int i = 0; i < 16; ++i) acc[i] = f32x4{0.f, 0.f, 0.f, 0.f};
    float zp = 0.f;

    for (int mt = 0; mt < 64; ++mt) {
        const int m0 = mt * 64;
        // A-frags: xt rows m (wave's m-quarter), hi/lo, 2 K-chunks
        const size_t ar = ((size_t)b * HW_ + m0 + mq * 16 + lm) * P_ + lq * 8;
        short8 aH0 = *reinterpret_cast<const short8*>(&xtTh[ar]);
        short8 aH1 = *reinterpret_cast<const short8*>(&xtTh[ar + 32]);
        short8 aL0 = *reinterpret_cast<const short8*>(&xtTl[ar]);
        short8 aL1 = *reinterpret_cast<const short8*>(&xtTl[ar + 32]);

        f32x4 s[4];
#pragma unroll
        for (int nt = 0; nt < 4; ++nt) s[nt] = f32x4{0.f, 0.f, 0.f, 0.f};
#pragma unroll
        for (int nt = 0; nt < 4; ++nt) {
            s[nt] = __builtin_amdgcn_mfma_f32_16x16x32_bf16(aH0, cB[nt][0][0], s[nt], 0, 0, 0);
            s[nt] = __builtin_amdgcn_mfma_f32_16x16x32_bf16(aH1, cB[nt][1][0], s[nt], 0, 0, 0);
            s[nt] = __builtin_amdgcn_mfma_f32_16x16x32_bf16(aH0, cB[nt][0][1], s[nt], 0, 0, 0);
            s[nt] = __builtin_amdgcn_mfma_f32_16x16x32_bf16(aH1, cB[nt][1][1], s[nt], 0, 0, 0);
            s[nt] = __builtin_amdgcn_mfma_f32_16x16x32_bf16(aL0, cB[nt][0][0], s[nt], 0, 0, 0);
            s[nt] = __builtin_amdgcn_mfma_f32_16x16x32_bf16(aL1, cB[nt][1][0], s[nt], 0, 0, 0);
        }
        __syncthreads();   // P region free (prev PV done)
        // exp + store P[n][m]: reg r -> m = mq*16 + lq*4 + r (contiguous)
#pragma unroll
        for (int nt = 0; nt < 4; ++nt) {
            const float e0 = __expf(s[nt][0]), e1 = __expf(s[nt][1]);
            const float e2 = __expf(s[nt][2]), e3 = __expf(s[nt][3]);
            zp += (e0 + e1) + (e2 + e3);
            short4v pk = { bfbits(e0), bfbits(e1), bfbits(e2), bfbits(e3) };
            *reinterpret_cast<short4v*>(&Ps[nt * 16 + lm][mq * 16 + lq * 4]) = pk;
        }
        __syncthreads();   // P ready

        // PV: A = P[nq-rows], B = xb[c][m] (global row-gather, L1/L2-hot)
        short8 pa0 = *reinterpret_cast<const short8*>(&Ps[nq * 16 + lm][lq * 8]);
        short8 pa1 = *reinterpret_cast<const short8*>(&Ps[nq * 16 + lm][32 + lq * 8]);
        const size_t xbb = ((size_t)b * C_) * HW_ + m0 + lq * 8;
#pragma unroll
        for (int ct = 0; ct < 16; ++ct) {
            const size_t cr = xbb + (size_t)(ct * 16 + lm) * HW_;
            short8 b0 = *reinterpret_cast<const short8*>(&xb[cr]);
            short8 b1 = *reinterpret_cast<const short8*>(&xb[cr + 32]);
            acc[ct] = __builtin_amdgcn_mfma_f32_16x16x32_bf16(pa0, b0, acc[ct], 0, 0, 0);
            acc[ct] = __builtin_amdgcn_mfma_f32_16x16x32_bf16(pa1, b1, acc[ct], 0, 0, 0);
        }
    }

    // Z: block reduction -> one atomicAdd
#pragma unroll
    for (int o = 32; o > 0; o >>= 1) zp += __shfl_down(zp, o, 64);
    if (lane == 0) zred[wv] = zp;
    __syncthreads();
    if (t == 0) atomicAdd(&Z[b], (zred[0] + zred[1]) + (zred[2] + zred[3]));

    // O[n][c] stores (coalesced along c, 64 B segments)
#pragma unroll
    for (int ct = 0; ct < 16; ++ct) {
        const int c = ct * 16 + lm;
#pragma unroll
        for (int r = 0; r < 4; ++r) {
            const int n = n0 + nq * 16 + lq * 4 + r;
            O[((size_t)b * HW_ + n) * C_ + c] = acc[ct][r];
        }
    }
}

// ---------------------------------------------------------------------------
// K4: y = x + O*(1/Z[b]) (flat reinterpretation add; 1024 blocks per batch).
// ---------------------------------------------------------------------------
__global__ __launch_bounds__(256) void k_add(
    const float* __restrict__ x, const float* __restrict__ o,
    const float* __restrict__ Z, float* __restrict__ y)
{
    const int bidx = blockIdx.x;
    const float invZ = 1.0f / Z[bidx >> 10];
    const size_t i = ((size_t)bidx * 256 + threadIdx.x) * 4;
    const float4 a = *reinterpret_cast<const float4*>(&x[i]);
    const float4 b = *reinterpret_cast<const float4*>(&o[i]);
    float4 r{fmaf(b.x, invZ, a.x), fmaf(b.y, invZ, a.y),
             fmaf(b.z, invZ, a.z), fmaf(b.w, invZ, a.w)};
    *reinterpret_cast<float4*>(&y[i]) = r;
}

extern "C" void kernel_launch(void* const* d_in, const int* in_sizes, int n_in,
                              void* d_out, int out_size, void* d_ws, size_t ws_size,
                              hipStream_t stream)
{
    const float* x   = (const float*)d_in[0];
    const float* wt  = (const float*)d_in[1];
    const float* bt  = (const float*)d_in[2];
    const float* wc  = (const float*)d_in[3];
    const float* bc  = (const float*)d_in[4];
    const float* wbo = (const float*)d_in[5];
    const float* bbo = (const float*)d_in[6];
    const float* wo  = (const float*)d_in[7];
    const float* bo  = (const float*)d_in[8];
    float* out = (float*)d_out;

    uint8_t* w8 = (uint8_t*)d_ws;
    const size_t MB = 1u << 20;
    // Phase 1 (until k_attn done): [0,32MB) = xtT/xcT hi/lo + xb bf16
    __hip_bfloat16* xtTh = (__hip_bfloat16*)(w8);            //  4 MB
    __hip_bfloat16* xtTl = (__hip_bfloat16*)(w8 + 4 * MB);   //  4 MB
    __hip_bfloat16* xcTh = (__hip_bfloat16*)(w8 + 8 * MB);   //  4 MB
    __hip_bfloat16* xcTl = (__hip_bfloat16*)(w8 + 12 * MB);  //  4 MB
    __hip_bfloat16* xbB  = (__hip_bfloat16*)(w8 + 16 * MB);  // 16 MB
    // Phase 2: y reuses [0,32MB)
    float* y = (float*)(w8);                                 // 32 MB
    float* O = (float*)(w8 + 32 * MB);                       // 32 MB
    __hip_bfloat16* Wb1 = (__hip_bfloat16*)(w8 + 32 * MB);   // in O region (dead before attn writes O)
    __hip_bfloat16* Wb2 = (__hip_bfloat16*)(w8 + 64 * MB);   // 1.2 MB
    float* Z = (float*)(w8 + 66 * MB);

    hipMemsetAsync(Z, 0, B_ * sizeof(float), stream);
    k_prep_w<<<dim3(2304), 256, 0, stream>>>(wbo, Wb1);
    k_conv1x1<<<dim3(16, 2, 8), 256, 0, stream>>>(x, wt, bt, wc, bc,
                                                  xtTh, xtTl, xcTh, xcTl);
    k_conv3x3_mfma<__hip_bfloat16><<<dim3(64, 8), 256, 0, stream>>>(x, Wb1, bbo, xbB);
    k_attn_mfma<<<dim3(64, 8), 256, 0, stream>>>(xtTh, xtTl, xcTh, xcTl, xbB, O, Z);
    k_prep_w<<<dim3(2304), 256, 0, stream>>>(wo, Wb2);
    k_add<<<dim3(8192), 256, 0, stream>>>(x, O, Z, y);
    k_conv3x3_mfma<float><<<dim3(64, 8), 256, 0, stream>>>(y, Wb2, bo, out);
}